// Round 1
// 1056.355 us; speedup vs baseline: 1.0287x; 1.0287x over previous
//
#include <hip/hip_runtime.h>

// APPNP: h0 = relu(x@W1+b1)@W2+b2 ; 10x: h = 0.9*(D^-1/2 A_sl D^-1/2 h) + 0.1*h0
// R2 build pipeline: bin edges by dst-bucket (64 nodes/bucket) with LDS-aggregated
//   reservation, then per-bucket CSR build entirely in LDS (coalesced final writes).
// R2 prop: store hs = dinv*h (fp16); gather loop is a pure sum (no per-edge dinv).
// R3 mlp rework (counters: MfmaUtil 7%, BANK_CONFLICT 1.46e7, occ 19%):
//   - W1/W2 pre-packed into MFMA fragment order -> B-frags load global->VGPR,
//     perfectly coalesced, no LDS staging for weights (was 1KB-stride uncoalesced).
//   - h1s XOR-swizzled (byte ^= (row&7)<<4): kills the 16-way bank conflict on
//     GEMM2's stride-512B ds_read_b128.
//   - LDS 64KB -> 32KB (xs dbuf 10KB aliased with h1s 32KB); x tile double-buffered,
//     loads issued pre-barrier.

typedef unsigned short u16;
typedef unsigned int   u32;
typedef __bf16    bfx8  __attribute__((ext_vector_type(8)));
typedef _Float16  h16x8 __attribute__((ext_vector_type(8)));
typedef float     f32x4 __attribute__((ext_vector_type(4)));

#define CAP 4096      // per-bucket edge capacity (mean 2048, sigma 45 -> 45 sigma margin)
#define EPB 16384     // edges per binscat block
#define NBMAX 1792    // bucket count upper bound for LDS arrays (N<=114k)

__device__ __forceinline__ u16 f2bf(float f) {
    u32 u = __float_as_uint(f);
    u += 0x7fffu + ((u >> 16) & 1u);   // RNE
    return (u16)(u >> 16);
}

// ---------------- build pass 1: bin edges by dst bucket ----------------

__global__ __launch_bounds__(256) void binscat_kernel(
        const int* __restrict__ src, const int* __restrict__ dst,
        int* __restrict__ gcur, u32* __restrict__ binned, int E, int NB) {
    __shared__ int cnt[NBMAX];
    int tid = threadIdx.x;
#pragma unroll
    for (int j = 0; j < NBMAX / 256; ++j) cnt[tid + j * 256] = 0;
    __syncthreads();
    int e0 = blockIdx.x * EPB;
    // count
    for (int r = 0; r < EPB / 256; ++r) {
        int i = e0 + r * 256 + tid;
        if (i < E) atomicAdd(&cnt[dst[i] >> 6], 1);
    }
    __syncthreads();
    // reserve: one global atomic per (block,bucket); cnt[b] becomes global cursor
    for (int j = 0; j < NBMAX / 256; ++j) {
        int b = tid + j * 256;
        if (b < NB) {
            int c = cnt[b];
            cnt[b] = (c > 0) ? atomicAdd(&gcur[b], c) : 0;
        }
    }
    __syncthreads();
    // place: pack (local_dst<<17)|src into 4B
    for (int r = 0; r < EPB / 256; ++r) {
        int i = e0 + r * 256 + tid;
        if (i < E) {
            int d = dst[i];
            int s = src[i];
            int bb = d >> 6;
            int p = atomicAdd(&cnt[bb], 1);
            if (p < CAP) binned[(size_t)bb * CAP + p] = ((u32)(d & 63) << 17) | (u32)s;
        }
    }
}

// ---------------- build pass 2: exclusive scan of bucket counts ----------------

__global__ __launch_bounds__(256) void bucket_scan_kernel(
        const int* __restrict__ gcur, int* __restrict__ bbase,
        int* __restrict__ rp, int N, int NB) {
    __shared__ int tsum[256];
    int tid = threadIdx.x;
    int loc[7];
    int run = 0;
#pragma unroll
    for (int j = 0; j < 7; ++j) {
        int b = tid * 7 + j;
        int v = 0;
        if (b < NB) { v = gcur[b]; if (v > CAP) v = CAP; }
        loc[j] = run;
        run += v;
    }
    tsum[tid] = run;
    __syncthreads();
    for (int off = 1; off < 256; off <<= 1) {
        int t = (tid >= off) ? tsum[tid - off] : 0;
        __syncthreads();
        tsum[tid] += t;
        __syncthreads();
    }
    int texcl = tsum[tid] - run;
#pragma unroll
    for (int j = 0; j < 7; ++j) {
        int b = tid * 7 + j;
        if (b < NB) bbase[b] = texcl + loc[j];
    }
    if (tid == 255) rp[N] = tsum[255];   // == E
}

// ---------------- build pass 3: per-bucket CSR in LDS (+rp,+dinv) ----------------

__global__ __launch_bounds__(256) void buildcsr_kernel(
        const u32* __restrict__ binned, const int* __restrict__ gcur,
        const int* __restrict__ bbase, int* __restrict__ rp,
        float* __restrict__ dinv, int* __restrict__ csr, int N) {
    __shared__ u32 eb[CAP];        // staged packed edges (16 KB)
    __shared__ int lcsr[CAP];      // bucket-local csr (16 KB)
    __shared__ int ncnt[64];
    __shared__ int lcur[64];
    int b = blockIdx.x;
    int tid = threadIdx.x;
    int cnt = gcur[b]; if (cnt > CAP) cnt = CAP;
    int base = bbase[b];
    if (tid < 64) ncnt[tid] = 0;
    __syncthreads();
    for (int idx = tid; idx < cnt; idx += 256) {
        u32 v = binned[(size_t)b * CAP + idx];
        eb[idx] = v;
        atomicAdd(&ncnt[v >> 17], 1);
    }
    __syncthreads();
    if (tid < 64) {   // wave 0: 64-wide exclusive scan + rp/dinv emit
        int c = ncnt[tid];
        int s = c;
#pragma unroll
        for (int off = 1; off < 64; off <<= 1) {
            int t = __shfl_up(s, off);
            if (tid >= off) s += t;
        }
        int excl = s - c;
        lcur[tid] = excl;
        int node = b * 64 + tid;
        if (node < N) {
            rp[node] = base + excl;
            dinv[node] = rsqrtf(1.0f + (float)c);   // +1 self-loop
        }
    }
    __syncthreads();
    for (int idx = tid; idx < cnt; idx += 256) {
        u32 v = eb[idx];
        int p = atomicAdd(&lcur[v >> 17], 1);
        lcsr[p] = (int)(v & 0x1FFFFu);
    }
    __syncthreads();
    for (int idx = tid; idx < cnt; idx += 256)
        csr[base + idx] = lcsr[idx];   // fully coalesced
}

// ---------------- weight pre-pack to MFMA fragment order (bf16) ----------------
// W1f frag f = ((t*4 + w)*4 + nt)*64 + lane, t<16 (K-step), w<4 (wave), nt<4.
//   elem j: W1[k = t*32 + (lane>>4)*8 + j][n = w*64 + nt*16 + (lane&15)]
// -> per (t,w,nt) the 64 lanes are 16B-contiguous: global_load_dwordx4 coalesced.

__global__ void prepw1_kernel(const float* __restrict__ W1, u16* __restrict__ W1f) {
    int f = blockIdx.x * 256 + threadIdx.x;   // 16384 frags
    int lane = f & 63;
    int nt = (f >> 6) & 3;
    int w  = (f >> 8) & 3;
    int t  = f >> 10;
    int col = w * 64 + nt * 16 + (lane & 15);
    int k0  = t * 32 + ((lane >> 4) << 3);
    u32 pk[4];
#pragma unroll
    for (int j = 0; j < 4; ++j) {
        u16 lo = f2bf(W1[(size_t)(k0 + 2 * j) * 256 + col]);
        u16 hi = f2bf(W1[(size_t)(k0 + 2 * j + 1) * 256 + col]);
        pk[j] = (u32)lo | ((u32)hi << 16);
    }
    *(uint4*)&W1f[(size_t)f * 8] = make_uint4(pk[0], pk[1], pk[2], pk[3]);
}

// W2f frag f = (t*4 + nt)*64 + lane, t<8, nt<4.
//   elem j: W2[k = t*32 + (lane>>4)*8 + j][n = nt*16 + (lane&15)]
__global__ void prepw2_kernel(const float* __restrict__ W2, u16* __restrict__ W2f) {
    int f = blockIdx.x * 256 + threadIdx.x;   // 2048 frags
    int lane = f & 63;
    int nt = (f >> 6) & 3;
    int t  = f >> 8;
    int col = nt * 16 + (lane & 15);
    int k0  = t * 32 + ((lane >> 4) << 3);
    u32 pk[4];
#pragma unroll
    for (int j = 0; j < 4; ++j) {
        u16 lo = f2bf(W2[(size_t)(k0 + 2 * j) * 64 + col]);
        u16 hi = f2bf(W2[(size_t)(k0 + 2 * j + 1) * 64 + col]);
        pk[j] = (u32)lo | ((u32)hi << 16);
    }
    *(uint4*)&W2f[(size_t)f * 8] = make_uint4(pk[0], pk[1], pk[2], pk[3]);
}

// ---------------- fused MLP -> h0 (fp32) and hs = dinv*h0 (fp16) ----------------
// block: 64 rows of x, 256 threads (4 waves). GEMM1: wave w covers hidden cols [64w,64w+64).
// mfma_f32_16x16x32_bf16: A[m=lane&15][k=(lane>>4)*8+j]; B[n=lane&15][k=same]; D col=lane&15,row=(lane>>4)*4+r
// B operands come straight from global (pre-packed frag order); only x is LDS-staged (dbuf).
// h1s swizzled: u16 col' = col ^ ((row&7)<<3)  -> 2-way banks on stride-512B b128 reads.

__global__ __launch_bounds__(256) void mlp_kernel(
        const float* __restrict__ x, const u16* __restrict__ W1f,
        const float* __restrict__ b1, const u16* __restrict__ W2f,
        const float* __restrict__ b2, const float* __restrict__ dinv,
        float* __restrict__ h0, _Float16* __restrict__ hA, int N) {
    __shared__ char lds[32768];
    u16* xs  = (u16*)lds;              // phase1: [2][64][40] u16 dbuf (10240 B)
    u16* h1s = (u16*)lds;              // phase2: [64][256] u16 swizzled (32768 B)

    const int tid  = threadIdx.x;
    const int wave = tid >> 6;
    const int lane = tid & 63;
    const int lq   = lane >> 4;        // quad
    const int lr   = lane & 15;
    const int blockRow = blockIdx.x * 64;

    // x staging coords: thread -> (row sr, 8-col chunk sc)
    const int sr = tid >> 2;
    const int sc = (tid & 3) << 3;
    const int gr = blockRow + sr;
    const bool haveRow = (gr < N);
    const float* xp = x + (size_t)(haveRow ? gr : 0) * 512 + sc;

    f32x4 acc[4][4];                   // [mt][nt]
#pragma unroll
    for (int a = 0; a < 4; ++a)
#pragma unroll
        for (int b = 0; b < 4; ++b) acc[a][b] = (f32x4){0.f, 0.f, 0.f, 0.f};

    // prologue: stage x tile 0 into buf 0
    {
        float v[8];
#pragma unroll
        for (int j = 0; j < 8; ++j) v[j] = 0.f;
        if (haveRow) {
            float4 u0 = *(const float4*)(xp);
            float4 u1 = *(const float4*)(xp + 4);
            v[0]=u0.x; v[1]=u0.y; v[2]=u0.z; v[3]=u0.w;
            v[4]=u1.x; v[5]=u1.y; v[6]=u1.z; v[7]=u1.w;
        }
        u32 pk[4];
#pragma unroll
        for (int j = 0; j < 4; ++j)
            pk[j] = (u32)f2bf(v[2*j]) | ((u32)f2bf(v[2*j+1]) << 16);
        *(uint4*)&xs[sr * 40 + sc] = make_uint4(pk[0], pk[1], pk[2], pk[3]);
    }

    const bfx8* w1q = (const bfx8*)W1f;

    // ---- GEMM1: K=512 in 16 steps of 32 ----
    for (int t = 0; t < 16; ++t) {
        // B frags for this step: global, coalesced, no barrier dependency
        bfx8 fb0 = w1q[(t * 16 + wave * 4 + 0) * 64 + lane];
        bfx8 fb1 = w1q[(t * 16 + wave * 4 + 1) * 64 + lane];
        bfx8 fb2 = w1q[(t * 16 + wave * 4 + 2) * 64 + lane];
        bfx8 fb3 = w1q[(t * 16 + wave * 4 + 3) * 64 + lane];
        // prefetch next x tile into regs (stored to LDS after MFMAs)
        float v[8];
#pragma unroll
        for (int j = 0; j < 8; ++j) v[j] = 0.f;
        if (t < 15 && haveRow) {
            const float* p = xp + (t + 1) * 32;
            float4 u0 = *(const float4*)(p);
            float4 u1 = *(const float4*)(p + 4);
            v[0]=u0.x; v[1]=u0.y; v[2]=u0.z; v[3]=u0.w;
            v[4]=u1.x; v[5]=u1.y; v[6]=u1.z; v[7]=u1.w;
        }
        __syncthreads();
        const u16* cur = xs + (t & 1) * 2560;
        bfx8 fa[4];
#pragma unroll
        for (int mt = 0; mt < 4; ++mt)
            fa[mt] = *(const bfx8*)&cur[(mt * 16 + lr) * 40 + lq * 8];
#pragma unroll
        for (int mt = 0; mt < 4; ++mt) {
            acc[mt][0] = __builtin_amdgcn_mfma_f32_16x16x32_bf16(fa[mt], fb0, acc[mt][0], 0, 0, 0);
            acc[mt][1] = __builtin_amdgcn_mfma_f32_16x16x32_bf16(fa[mt], fb1, acc[mt][1], 0, 0, 0);
            acc[mt][2] = __builtin_amdgcn_mfma_f32_16x16x32_bf16(fa[mt], fb2, acc[mt][2], 0, 0, 0);
            acc[mt][3] = __builtin_amdgcn_mfma_f32_16x16x32_bf16(fa[mt], fb3, acc[mt][3], 0, 0, 0);
        }
        if (t < 15) {
            u16* nxt = xs + ((t + 1) & 1) * 2560;
            u32 pk[4];
#pragma unroll
            for (int j = 0; j < 4; ++j)
                pk[j] = (u32)f2bf(v[2*j]) | ((u32)f2bf(v[2*j+1]) << 16);
            *(uint4*)&nxt[sr * 40 + sc] = make_uint4(pk[0], pk[1], pk[2], pk[3]);
        }
    }
    __syncthreads();   // all fa reads done; reuse LDS as h1s

    // ---- epilogue1: bias+relu -> h1s (bf16, swizzled) ----
#pragma unroll
    for (int nt = 0; nt < 4; ++nt) {
        int col = wave * 64 + nt * 16 + lr;
        float bb = b1[col];
#pragma unroll
        for (int mt = 0; mt < 4; ++mt)
#pragma unroll
            for (int r = 0; r < 4; ++r) {
                int row = mt * 16 + lq * 4 + r;
                float vv = acc[mt][nt][r] + bb;
                vv = vv > 0.f ? vv : 0.f;
                h1s[row * 256 + (col ^ ((row & 7) << 3))] = f2bf(vv);
            }
    }
    __syncthreads();

    // ---- GEMM2: wave w -> rows [16w,16w+16), cols 0..63, K=256 ----
    f32x4 acc2[4];
#pragma unroll
    for (int a = 0; a < 4; ++a) acc2[a] = (f32x4){0.f, 0.f, 0.f, 0.f};
    const bfx8* w2q = (const bfx8*)W2f;
    const int row2 = wave * 16 + lr;
    const int sw2  = (row2 & 7) << 3;
#pragma unroll
    for (int t2 = 0; t2 < 8; ++t2) {
        bfx8 a = *(const bfx8*)&h1s[row2 * 256 + ((t2 * 32 + lq * 8) ^ sw2)];
#pragma unroll
        for (int nt = 0; nt < 4; ++nt) {
            bfx8 b = w2q[(t2 * 4 + nt) * 64 + lane];
            acc2[nt] = __builtin_amdgcn_mfma_f32_16x16x32_bf16(a, b, acc2[nt], 0, 0, 0);
        }
    }

    // ---- epilogue2: bias, store h0 (fp32) and hs=dinv*h0 (fp16) ----
#pragma unroll
    for (int nt = 0; nt < 4; ++nt) {
        int col = nt * 16 + lr;
        float bb = b2[col];
#pragma unroll
        for (int r = 0; r < 4; ++r) {
            int row = wave * 16 + lq * 4 + r;
            int g = blockRow + row;
            if (g < N) {
                float vv = acc2[nt][r] + bb;
                size_t idx = (size_t)g * 64 + col;
                h0[idx] = vv;
                hA[idx] = (_Float16)(vv * dinv[g]);
            }
        }
    }
}

// ---------------- propagation: 8 threads/node, 16B/lane, pure-sum gather ----------------

template <typename OUTT>
__global__ __launch_bounds__(256) void prop_kernel(
        const _Float16* __restrict__ hs, const float* __restrict__ h0,
        const float* __restrict__ dinv, const int* __restrict__ rp,
        const int* __restrict__ csr, OUTT* __restrict__ hout, int N) {
    int t = blockIdx.x * 256 + threadIdx.x;
    int i = t >> 3;
    int l = t & 7;
    if (i >= N) return;
    int beg = rp[i], end = rp[i + 1];
    const _Float16* hb = hs + l * 8;
    h16x8 self = *(const h16x8*)(hb + (size_t)i * 64);
    float a[8];
#pragma unroll
    for (int j = 0; j < 8; ++j) a[j] = (float)self[j];   // self-loop folded into init
    int e = beg;
    for (; e + 1 < end; e += 2) {                        // 2x unroll for MLP
        int s0 = csr[e], s1 = csr[e + 1];
        h16x8 g0 = *(const h16x8*)(hb + (size_t)s0 * 64);
        h16x8 g1 = *(const h16x8*)(hb + (size_t)s1 * 64);
#pragma unroll
        for (int j = 0; j < 8; ++j) a[j] += (float)g0[j];
#pragma unroll
        for (int j = 0; j < 8; ++j) a[j] += (float)g1[j];
    }
    if (e < end) {
        int s0 = csr[e];
        h16x8 g0 = *(const h16x8*)(hb + (size_t)s0 * 64);
#pragma unroll
        for (int j = 0; j < 8; ++j) a[j] += (float)g0[j];
    }
    float dv = dinv[i];
    float c1 = 0.9f * dv;
    const float* h0p = h0 + (size_t)i * 64 + l * 8;
    float o[8];
#pragma unroll
    for (int j = 0; j < 8; ++j) o[j] = fmaf(c1, a[j], 0.1f * h0p[j]);
    if constexpr (sizeof(OUTT) == 2) {
        h16x8 ov;
#pragma unroll
        for (int j = 0; j < 8; ++j) ov[j] = (_Float16)(dv * o[j]);   // store hs_new
        *(h16x8*)(hout + (size_t)i * 64 + l * 8) = ov;
    } else {
        float4* q = (float4*)(hout + (size_t)i * 64 + l * 8);
        q[0] = make_float4(o[0], o[1], o[2], o[3]);
        q[1] = make_float4(o[4], o[5], o[6], o[7]);
    }
}

// ---------------- launch ----------------

extern "C" void kernel_launch(void* const* d_in, const int* in_sizes, int n_in,
                              void* d_out, int out_size, void* d_ws, size_t ws_size,
                              hipStream_t stream) {
    const float* x  = (const float*)d_in[0];
    const int*   ei = (const int*)d_in[1];
    const float* W1 = (const float*)d_in[2];
    const float* b1 = (const float*)d_in[3];
    const float* W2 = (const float*)d_in[4];
    const float* b2 = (const float*)d_in[5];
    const int N = in_sizes[0] / 512;
    const int E = in_sizes[1] / 2;
    const int NB = (N + 63) / 64;
    const int* src = ei;
    const int* dst = ei + E;

    char* w = (char*)d_ws;
    size_t off = 0;
    auto alloc = [&](size_t bytes) -> char* {
        char* p = w + off;
        off = (off + bytes + 1023) & ~(size_t)1023;
        return p;
    };
    int*      gcur  = (int*)alloc((size_t)NB * 4);
    int*      bbase = (int*)alloc((size_t)NB * 4);
    int*      rp    = (int*)alloc(((size_t)N + 1) * 4);
    float*    dinv  = (float*)alloc((size_t)N * 4);
    int*      csr   = (int*)alloc((size_t)E * 4);
    u32*      binned= (u32*)alloc((size_t)NB * CAP * 4);
    u16*      W1f   = (u16*)alloc(512 * 256 * 2);
    u16*      W2f   = (u16*)alloc(256 * 64 * 2);
    float*    h0    = (float*)alloc((size_t)N * 64 * 4);
    _Float16* hA    = (_Float16*)alloc((size_t)N * 64 * 2);
    _Float16* hB    = (_Float16*)alloc((size_t)N * 64 * 2);
    // ws use ~91 MB

    hipMemsetAsync(gcur, 0, (size_t)NB * 4, stream);
    binscat_kernel<<<(E + EPB - 1) / EPB, 256, 0, stream>>>(src, dst, gcur, binned, E, NB);
    bucket_scan_kernel<<<1, 256, 0, stream>>>(gcur, bbase, rp, N, NB);
    buildcsr_kernel<<<NB, 256, 0, stream>>>(binned, gcur, bbase, rp, dinv, csr, N);
    prepw1_kernel<<<64, 256, 0, stream>>>(W1, W1f);
    prepw2_kernel<<<8, 256, 0, stream>>>(W2, W2f);
    mlp_kernel<<<(N + 63) / 64, 256, 0, stream>>>(x, W1f, b1, W2f, b2, dinv, h0, hA, N);

    const _Float16* pin = hA;
    int grid = (N * 8 + 255) / 256;
    for (int it = 0; it < 9; ++it) {
        _Float16* pout = (it & 1) ? hA : hB;
        prop_kernel<_Float16><<<grid, 256, 0, stream>>>(pin, h0, dinv, rp, csr, pout, N);
        pin = pout;
    }
    prop_kernel<float><<<grid, 256, 0, stream>>>(pin, h0, dinv, rp, csr, (float*)d_out, N);
}